// Round 4
// baseline (1243.495 us; speedup 1.0000x reference)
//
#include <hip/hip_runtime.h>

#define ZN 131072          // B*H*W rows
#define DD 64              // embedding dim
#define KK 1024            // codebook entries
#define BSTRIDE 262144     // 64*64*64 (per-batch stride in z)
#define DSTRIDE 4096       // per-d stride in z (H*W)
#define ZQ_ELEMS 8388608   // 32*64*64*64

// ---- workspace layout ----
// [0,8)                double   loss accumulator
// [8,12)               unsigned flagged-row count
// [16,4112)            float    csq32[1024]    (numpy-emulated fp32)
// [4112,528400)        float    zsq32[131072]  (numpy-emulated fp32)
// [528400,1052688)     int      worklist[131072]
// [1052688,2101264)    u64      pack[131072]   (ordered_dist<<32 | k)
// [2101264,2363408)    float    cbT[64][1024]  (transposed codebook)
#define WS_CSQ_OFF   16
#define WS_ZSQ_OFF   4112
#define WS_WORK_OFF  528400
#define WS_PACK_OFF  1052688
#define WS_CBT_OFF   2101264

// numpy-emulated fp32 sum of a[i]^2 over 64 elems (pairwise, 8 accumulators).
__device__ __forceinline__ float np_sumsq64(const float* a) {
    float r0 = __fmul_rn(a[0], a[0]), r1 = __fmul_rn(a[1], a[1]);
    float r2 = __fmul_rn(a[2], a[2]), r3 = __fmul_rn(a[3], a[3]);
    float r4 = __fmul_rn(a[4], a[4]), r5 = __fmul_rn(a[5], a[5]);
    float r6 = __fmul_rn(a[6], a[6]), r7 = __fmul_rn(a[7], a[7]);
#pragma unroll
    for (int i = 8; i < 64; i += 8) {
        r0 = __fadd_rn(r0, __fmul_rn(a[i + 0], a[i + 0]));
        r1 = __fadd_rn(r1, __fmul_rn(a[i + 1], a[i + 1]));
        r2 = __fadd_rn(r2, __fmul_rn(a[i + 2], a[i + 2]));
        r3 = __fadd_rn(r3, __fmul_rn(a[i + 3], a[i + 3]));
        r4 = __fadd_rn(r4, __fmul_rn(a[i + 4], a[i + 4]));
        r5 = __fadd_rn(r5, __fmul_rn(a[i + 5], a[i + 5]));
        r6 = __fadd_rn(r6, __fmul_rn(a[i + 6], a[i + 6]));
        r7 = __fadd_rn(r7, __fmul_rn(a[i + 7], a[i + 7]));
    }
    return __fadd_rn(__fadd_rn(__fadd_rn(r0, r1), __fadd_rn(r2, r3)),
                     __fadd_rn(__fadd_rn(r4, r5), __fadd_rn(r6, r7)));
}

__global__ __launch_bounds__(256) void vq_csq(const float* __restrict__ cb,
                                              float* __restrict__ csq) {
    int k = blockIdx.x * 256 + threadIdx.x;
    csq[k] = np_sumsq64(cb + k * DD);
}

// cbT[d][k] = cb[k][d]
__global__ __launch_bounds__(256) void vq_transpose(const float* __restrict__ cb,
                                                    float* __restrict__ cbT) {
    int i = blockIdx.x * 256 + threadIdx.x;  // i = d*1024 + k
    int d = i >> 10, k = i & 1023;
    cbT[i] = cb[k * DD + d];
}

// -------- fp32 prefilter argmin --------
// block = 256 threads = 64 rows (tl) x 4 k-groups (kg); each thread: 1 row,
// 256 codes. z row register-resident (~90 VGPR, capped at 128 by launch
// bounds). Codebook loads wave-uniform (each wave = one kg) -> scalar loads.
// LDS merge of the 4 k-chunks: min2_global = min(winner.min2, losers.min1).
__global__ __launch_bounds__(256, 4) void vq_argmin(const float* __restrict__ z,
                                                    const float* __restrict__ cb,
                                                    const float* __restrict__ csq,
                                                    float* __restrict__ zsq32,
                                                    float* __restrict__ idxf_out,
                                                    unsigned* __restrict__ count,
                                                    int* __restrict__ worklist) {
    int tl = threadIdx.x & 63;
    int kg = threadIdx.x >> 6;
    int n = blockIdx.x * 64 + tl;
    int b = n >> 12, p = n & 4095;
    const float* zp = z + (size_t)b * BSTRIDE + p;

    float zr[DD];
#pragma unroll
    for (int d = 0; d < DD; ++d) zr[d] = zp[(size_t)d * DSTRIDE];  // coalesced

    if (kg == 0) zsq32[n] = np_sumsq64(zr);

    float min1 = 3.4e38f, min2 = 3.4e38f;
    int best = 0;
    int kbase = kg << 8;
    for (int kk = 0; kk < 256; ++kk) {
        int k = kbase + kk;
        const float* c = cb + k * DD;  // wave-uniform -> scalar loads
        float d0 = 0.f, d1 = 0.f, d2 = 0.f, d3 = 0.f;
#pragma unroll
        for (int d = 0; d < DD; d += 4) {
            d0 = fmaf(zr[d + 0], c[d + 0], d0);
            d1 = fmaf(zr[d + 1], c[d + 1], d1);
            d2 = fmaf(zr[d + 2], c[d + 2], d2);
            d3 = fmaf(zr[d + 3], c[d + 3], d3);
        }
        float dist = fmaf(-2.f, (d0 + d1) + (d2 + d3), csq[k]);
        bool lt = dist < min1;  // strict: keeps lowest k on ties
        float old1 = min1;
        min1 = lt ? dist : min1;
        min2 = lt ? old1 : fminf(min2, dist);
        best = lt ? k : best;
    }

    __shared__ float smin1[4][64];
    __shared__ float smin2[4][64];
    __shared__ int sbest[4][64];
    smin1[kg][tl] = min1;
    smin2[kg][tl] = min2;
    sbest[kg][tl] = best;
    __syncthreads();

    if (kg == 0) {
        float g1 = smin1[0][tl], g2 = smin2[0][tl];
        int gb = sbest[0][tl];
#pragma unroll
        for (int c = 1; c < 4; ++c) {
            float c1 = smin1[c][tl];
            if (c1 < g1) {                 // strict: ties keep lower-k chunk
                g2 = fminf(g1, smin2[c][tl]);
                gb = sbest[c][tl];
                g1 = c1;
            } else {
                g2 = fminf(g2, c1);
            }
        }
        idxf_out[n] = (float)gb;
        // reference fp32 rounding noise can only flip ranking for gaps
        // < ~1.2e-5; flag with wide margin -> exact emulation pass.
        if (g2 - g1 < 2e-4f) worklist[atomicAdd(count, 1u)] = n;
    }
}

// -------- reference-fp32-emulated argmin for flagged rows --------
// work item = (flagged row r, code k); lanes <-> consecutive k (coalesced cbT);
// each wave = 64 k's of one row -> shuffle-min -> one atomicMin per wave.
__global__ __launch_bounds__(256) void vq_refine(const float* __restrict__ z,
                                                 const float* __restrict__ cbT,
                                                 const float* __restrict__ csq,
                                                 const float* __restrict__ zsq32,
                                                 const unsigned* __restrict__ count,
                                                 const int* __restrict__ worklist,
                                                 unsigned long long* __restrict__ pack) {
    unsigned cnt = *count;
    unsigned long long total = (unsigned long long)cnt << 10;
    unsigned long long stride = (unsigned long long)gridDim.x * 256;
    for (unsigned long long w = blockIdx.x * 256 + threadIdx.x; w < total; w += stride) {
        unsigned r = (unsigned)(w >> 10);
        unsigned k = (unsigned)(w & 1023);
        int n = worklist[r];
        int b = n >> 12, p = n & 4095;
        const float* zp = z + (size_t)b * BSTRIDE + p;

        double a0 = 0.0, a1 = 0.0, a2 = 0.0, a3 = 0.0;
#pragma unroll
        for (int d = 0; d < DD; d += 4) {
            a0 = fma((double)zp[(size_t)(d + 0) * DSTRIDE], (double)cbT[(d + 0) * KK + k], a0);
            a1 = fma((double)zp[(size_t)(d + 1) * DSTRIDE], (double)cbT[(d + 1) * KK + k], a1);
            a2 = fma((double)zp[(size_t)(d + 2) * DSTRIDE], (double)cbT[(d + 2) * KK + k], a2);
            a3 = fma((double)zp[(size_t)(d + 3) * DSTRIDE], (double)cbT[(d + 3) * KK + k], a3);
        }
        double dot = (a0 + a1) + (a2 + a3);
        float twoC = (float)(2.0 * dot);               // ~sgemm output, correctly rounded
        float dist = __fsub_rn(__fadd_rn(zsq32[n], csq[k]), twoC);  // reference fp32 ops

        unsigned ub = __float_as_uint(dist);
        ub = (ub & 0x80000000u) ? ~ub : (ub | 0x80000000u);  // order-preserving map
        unsigned long long pk = ((unsigned long long)ub << 32) | k;  // ties -> lowest k
#pragma unroll
        for (int off = 32; off; off >>= 1) {
            unsigned long long o = (unsigned long long)__shfl_xor((long long)pk, off, 64);
            pk = pk < o ? pk : o;
        }
        if ((threadIdx.x & 63) == 0) atomicMin(&pack[r], pk);
    }
}

__global__ __launch_bounds__(256) void vq_writeback(const unsigned* __restrict__ count,
                                                    const int* __restrict__ worklist,
                                                    const unsigned long long* __restrict__ pack,
                                                    float* __restrict__ idxf_out) {
    unsigned i = blockIdx.x * 256 + threadIdx.x;
    if (i < *count)
        idxf_out[worklist[i]] = (float)(unsigned)(pack[i] & 0xFFFFFFFFull);
}

// -------- gather z_q + fused loss partial reduction --------
__global__ __launch_bounds__(256) void vq_gather_loss(const float* __restrict__ z,
                                                      const float* __restrict__ cb,
                                                      const float* __restrict__ idxf,
                                                      float* __restrict__ zq_out,
                                                      double* __restrict__ acc) {
    int n = blockIdx.x * 256 + threadIdx.x;
    int b = n >> 12, p = n & 4095;
    const float* zp = z + (size_t)b * BSTRIDE + p;
    float* qp = zq_out + (size_t)b * BSTRIDE + p;
    int k = (int)idxf[n];
    const float* c = cb + k * DD;

    float s = 0.f;
#pragma unroll
    for (int d = 0; d < DD; ++d) {
        float q = c[d];
        float diff = q - zp[(size_t)d * DSTRIDE];
        s = fmaf(diff, diff, s);
        qp[(size_t)d * DSTRIDE] = q;  // z_q_st == z_q numerically
    }

#pragma unroll
    for (int off = 32; off; off >>= 1) s += __shfl_down(s, off, 64);
    __shared__ float partial[4];
    if ((threadIdx.x & 63) == 0) partial[threadIdx.x >> 6] = s;
    __syncthreads();
    if (threadIdx.x == 0) {
        float t = (partial[0] + partial[1]) + (partial[2] + partial[3]);
        atomicAdd(acc, (double)t);
    }
}

__global__ void vq_finalize(const double* __restrict__ acc, float* __restrict__ loss_out) {
    *loss_out = (float)(1.25 * (*acc) / (double)ZQ_ELEMS);
}

extern "C" void kernel_launch(void* const* d_in, const int* in_sizes, int n_in,
                              void* d_out, int out_size, void* d_ws, size_t ws_size,
                              hipStream_t stream) {
    const float* z = (const float*)d_in[0];
    const float* cb = (const float*)d_in[1];
    float* out = (float*)d_out;

    float* zq_out = out;                   // [0, 8388608)
    float* loss_out = out + ZQ_ELEMS;      // [8388608]
    float* idxf_out = out + ZQ_ELEMS + 1;  // [8388609, +131072)

    char* ws = (char*)d_ws;
    double* acc = (double*)ws;
    unsigned* count = (unsigned*)(ws + 8);
    float* csq = (float*)(ws + WS_CSQ_OFF);
    float* zsq32 = (float*)(ws + WS_ZSQ_OFF);
    int* worklist = (int*)(ws + WS_WORK_OFF);
    unsigned long long* pack = (unsigned long long*)(ws + WS_PACK_OFF);
    float* cbT = (float*)(ws + WS_CBT_OFF);

    hipMemsetAsync(d_ws, 0, 16, stream);                        // acc=0, count=0
    hipMemsetAsync(ws + WS_PACK_OFF, 0xFF, ZN * 8, stream);     // pack = UINT64_MAX

    vq_csq<<<KK / 256, 256, 0, stream>>>(cb, csq);
    vq_transpose<<<KK * DD / 256, 256, 0, stream>>>(cb, cbT);
    vq_argmin<<<ZN / 64, 256, 0, stream>>>(z, cb, csq, zsq32, idxf_out, count, worklist);
    vq_refine<<<2048, 256, 0, stream>>>(z, cbT, csq, zsq32, count, worklist, pack);
    vq_writeback<<<ZN / 256, 256, 0, stream>>>(count, worklist, pack, idxf_out);
    vq_gather_loss<<<ZN / 256, 256, 0, stream>>>(z, cb, idxf_out, zq_out, acc);
    vq_finalize<<<1, 1, 0, stream>>>(acc, loss_out);
}

// Round 5
// 718.965 us; speedup vs baseline: 1.7296x; 1.7296x over previous
//
#include <hip/hip_runtime.h>

#define ZN 131072          // B*H*W rows
#define DD 64              // embedding dim
#define KK 1024            // codebook entries
#define BSTRIDE 262144     // 64*64*64 (per-batch stride in z)
#define DSTRIDE 4096       // per-d stride in z (H*W)
#define ZQ_ELEMS 8388608   // 32*64*64*64

// ---- workspace layout ----
// [0,8)                double   loss accumulator
// [8,12)               unsigned flagged-row count
// [16,4112)            float    csq32[1024]    (numpy-emulated fp32)
// [4112,528400)        float    zsq32[131072]  (numpy-emulated fp32)
// [528400,1052688)     int      worklist[131072]
// [1052688,2101264)    u64      pack[131072]   (ordered_dist<<32 | k)
// [2101264,2363408)    float    cbT[64][1024]  (transposed codebook)
#define WS_CSQ_OFF   16
#define WS_ZSQ_OFF   4112
#define WS_WORK_OFF  528400
#define WS_PACK_OFF  1052688
#define WS_CBT_OFF   2101264

typedef float v2f __attribute__((ext_vector_type(2)));

// numpy-emulated fp32 sum of a[i]^2 over 64 elems (pairwise, 8 accumulators).
__device__ __forceinline__ float np_sumsq64(const float* a) {
    float r0 = __fmul_rn(a[0], a[0]), r1 = __fmul_rn(a[1], a[1]);
    float r2 = __fmul_rn(a[2], a[2]), r3 = __fmul_rn(a[3], a[3]);
    float r4 = __fmul_rn(a[4], a[4]), r5 = __fmul_rn(a[5], a[5]);
    float r6 = __fmul_rn(a[6], a[6]), r7 = __fmul_rn(a[7], a[7]);
#pragma unroll
    for (int i = 8; i < 64; i += 8) {
        r0 = __fadd_rn(r0, __fmul_rn(a[i + 0], a[i + 0]));
        r1 = __fadd_rn(r1, __fmul_rn(a[i + 1], a[i + 1]));
        r2 = __fadd_rn(r2, __fmul_rn(a[i + 2], a[i + 2]));
        r3 = __fadd_rn(r3, __fmul_rn(a[i + 3], a[i + 3]));
        r4 = __fadd_rn(r4, __fmul_rn(a[i + 4], a[i + 4]));
        r5 = __fadd_rn(r5, __fmul_rn(a[i + 5], a[i + 5]));
        r6 = __fadd_rn(r6, __fmul_rn(a[i + 6], a[i + 6]));
        r7 = __fadd_rn(r7, __fmul_rn(a[i + 7], a[i + 7]));
    }
    return __fadd_rn(__fadd_rn(__fadd_rn(r0, r1), __fadd_rn(r2, r3)),
                     __fadd_rn(__fadd_rn(r4, r5), __fadd_rn(r6, r7)));
}

__global__ __launch_bounds__(256) void vq_csq(const float* __restrict__ cb,
                                              float* __restrict__ csq) {
    int k = blockIdx.x * 256 + threadIdx.x;
    csq[k] = np_sumsq64(cb + k * DD);
}

// cbT[d][k] = cb[k][d]
__global__ __launch_bounds__(256) void vq_transpose(const float* __restrict__ cb,
                                                    float* __restrict__ cbT) {
    int i = blockIdx.x * 256 + threadIdx.x;  // i = d*1024 + k
    int d = i >> 10, k = i & 1023;
    cbT[i] = cb[k * DD + d];
}

// -------- fp32 prefilter argmin: 1 row/thread, packed-fp32 inner loop ------
// k is a uniform loop var -> codebook & csq come in via s_load (SGPR
// broadcast, 0 VALU cost). z row lives in 32 x float2 VGPRs; waves_per_eu(2,2)
// grants 256 VGPRs so the compiler cannot spill it. Inner dot uses
// __builtin_elementwise_fma on float2 -> v_pk_fma_f32 (2 MACs/inst).
__global__ __attribute__((amdgpu_waves_per_eu(2, 2))) __launch_bounds__(256)
void vq_argmin(const float* __restrict__ z,
               const float* __restrict__ cb,
               const float* __restrict__ csq,
               float* __restrict__ zsq32,
               float* __restrict__ idxf_out,
               unsigned* __restrict__ count,
               int* __restrict__ worklist) {
    int n = blockIdx.x * 256 + threadIdx.x;
    int b = n >> 12, p = n & 4095;
    const float* zp = z + (size_t)b * BSTRIDE + p;

    v2f zr[32];
#pragma unroll
    for (int j = 0; j < 32; ++j) {  // coalesced across lanes (stride-4096 per d)
        zr[j].x = zp[(size_t)(2 * j + 0) * DSTRIDE];
        zr[j].y = zp[(size_t)(2 * j + 1) * DSTRIDE];
    }

    // numpy-emulated fp32 ||z||^2 (same pairwise-8 order as np.sum)
    {
#define ZA(i) (((i) & 1) ? zr[(i) >> 1].y : zr[(i) >> 1].x)
        float r[8];
#pragma unroll
        for (int j = 0; j < 8; ++j) r[j] = __fmul_rn(ZA(j), ZA(j));
#pragma unroll
        for (int i = 8; i < 64; i += 8)
#pragma unroll
            for (int j = 0; j < 8; ++j)
                r[j] = __fadd_rn(r[j], __fmul_rn(ZA(i + j), ZA(i + j)));
        zsq32[n] = __fadd_rn(__fadd_rn(__fadd_rn(r[0], r[1]), __fadd_rn(r[2], r[3])),
                             __fadd_rn(__fadd_rn(r[4], r[5]), __fadd_rn(r[6], r[7])));
#undef ZA
    }

    float min1 = 3.4e38f, min2 = 3.4e38f;
    int best = 0;
#pragma unroll 2
    for (int k = 0; k < KK; ++k) {  // k uniform -> scalar loads
        const v2f* c = (const v2f*)(cb + k * DD);
        v2f a0 = {0.f, 0.f}, a1 = {0.f, 0.f}, a2 = {0.f, 0.f}, a3 = {0.f, 0.f};
#pragma unroll
        for (int j = 0; j < 32; j += 4) {
            a0 = __builtin_elementwise_fma(zr[j + 0], c[j + 0], a0);
            a1 = __builtin_elementwise_fma(zr[j + 1], c[j + 1], a1);
            a2 = __builtin_elementwise_fma(zr[j + 2], c[j + 2], a2);
            a3 = __builtin_elementwise_fma(zr[j + 3], c[j + 3], a3);
        }
        v2f s = (a0 + a1) + (a2 + a3);
        float dot = s.x + s.y;
        float dist = fmaf(-2.f, dot, csq[k]);
        bool lt = dist < min1;  // strict: keeps lowest k on ties
        float old1 = min1;
        min1 = lt ? dist : min1;
        min2 = lt ? old1 : fminf(min2, dist);
        best = lt ? k : best;
    }

    idxf_out[n] = (float)best;
    // reference fp32 rounding noise can only flip ranking for gaps < ~3e-5;
    // flag with wide margin -> exact reference-arithmetic emulation pass.
    if (min2 - min1 < 2e-4f) worklist[atomicAdd(count, 1u)] = n;
}

// -------- reference-fp32-emulated argmin for flagged rows --------
// work item = (flagged row r, code k); lanes <-> consecutive k (coalesced cbT);
// each wave = 64 k's of one row -> shuffle-min -> one atomicMin per wave.
__global__ __launch_bounds__(256) void vq_refine(const float* __restrict__ z,
                                                 const float* __restrict__ cbT,
                                                 const float* __restrict__ csq,
                                                 const float* __restrict__ zsq32,
                                                 const unsigned* __restrict__ count,
                                                 const int* __restrict__ worklist,
                                                 unsigned long long* __restrict__ pack) {
    unsigned cnt = *count;
    unsigned long long total = (unsigned long long)cnt << 10;
    unsigned long long stride = (unsigned long long)gridDim.x * 256;
    for (unsigned long long w = blockIdx.x * 256 + threadIdx.x; w < total; w += stride) {
        unsigned r = (unsigned)(w >> 10);
        unsigned k = (unsigned)(w & 1023);
        int n = worklist[r];
        int b = n >> 12, p = n & 4095;
        const float* zp = z + (size_t)b * BSTRIDE + p;

        double a0 = 0.0, a1 = 0.0, a2 = 0.0, a3 = 0.0;
#pragma unroll
        for (int d = 0; d < DD; d += 4) {
            a0 = fma((double)zp[(size_t)(d + 0) * DSTRIDE], (double)cbT[(d + 0) * KK + k], a0);
            a1 = fma((double)zp[(size_t)(d + 1) * DSTRIDE], (double)cbT[(d + 1) * KK + k], a1);
            a2 = fma((double)zp[(size_t)(d + 2) * DSTRIDE], (double)cbT[(d + 2) * KK + k], a2);
            a3 = fma((double)zp[(size_t)(d + 3) * DSTRIDE], (double)cbT[(d + 3) * KK + k], a3);
        }
        double dot = (a0 + a1) + (a2 + a3);
        float twoC = (float)(2.0 * dot);               // ~sgemm output, correctly rounded
        float dist = __fsub_rn(__fadd_rn(zsq32[n], csq[k]), twoC);  // reference fp32 ops

        unsigned ub = __float_as_uint(dist);
        ub = (ub & 0x80000000u) ? ~ub : (ub | 0x80000000u);  // order-preserving map
        unsigned long long pk = ((unsigned long long)ub << 32) | k;  // ties -> lowest k
#pragma unroll
        for (int off = 32; off; off >>= 1) {
            unsigned long long o = (unsigned long long)__shfl_xor((long long)pk, off, 64);
            pk = pk < o ? pk : o;
        }
        if ((threadIdx.x & 63) == 0) atomicMin(&pack[r], pk);
    }
}

__global__ __launch_bounds__(256) void vq_writeback(const unsigned* __restrict__ count,
                                                    const int* __restrict__ worklist,
                                                    const unsigned long long* __restrict__ pack,
                                                    float* __restrict__ idxf_out) {
    unsigned i = blockIdx.x * 256 + threadIdx.x;
    if (i < *count)
        idxf_out[worklist[i]] = (float)(unsigned)(pack[i] & 0xFFFFFFFFull);
}

// -------- gather z_q + fused loss partial reduction --------
__global__ __launch_bounds__(256) void vq_gather_loss(const float* __restrict__ z,
                                                      const float* __restrict__ cb,
                                                      const float* __restrict__ idxf,
                                                      float* __restrict__ zq_out,
                                                      double* __restrict__ acc) {
    int n = blockIdx.x * 256 + threadIdx.x;
    int b = n >> 12, p = n & 4095;
    const float* zp = z + (size_t)b * BSTRIDE + p;
    float* qp = zq_out + (size_t)b * BSTRIDE + p;
    int k = (int)idxf[n];
    const float* c = cb + k * DD;

    float s = 0.f;
#pragma unroll
    for (int d = 0; d < DD; ++d) {
        float q = c[d];
        float diff = q - zp[(size_t)d * DSTRIDE];
        s = fmaf(diff, diff, s);
        qp[(size_t)d * DSTRIDE] = q;  // z_q_st == z_q numerically
    }

#pragma unroll
    for (int off = 32; off; off >>= 1) s += __shfl_down(s, off, 64);
    __shared__ float partial[4];
    if ((threadIdx.x & 63) == 0) partial[threadIdx.x >> 6] = s;
    __syncthreads();
    if (threadIdx.x == 0) {
        float t = (partial[0] + partial[1]) + (partial[2] + partial[3]);
        atomicAdd(acc, (double)t);
    }
}

__global__ void vq_finalize(const double* __restrict__ acc, float* __restrict__ loss_out) {
    *loss_out = (float)(1.25 * (*acc) / (double)ZQ_ELEMS);
}

extern "C" void kernel_launch(void* const* d_in, const int* in_sizes, int n_in,
                              void* d_out, int out_size, void* d_ws, size_t ws_size,
                              hipStream_t stream) {
    const float* z = (const float*)d_in[0];
    const float* cb = (const float*)d_in[1];
    float* out = (float*)d_out;

    float* zq_out = out;                   // [0, 8388608)
    float* loss_out = out + ZQ_ELEMS;      // [8388608]
    float* idxf_out = out + ZQ_ELEMS + 1;  // [8388609, +131072)

    char* ws = (char*)d_ws;
    double* acc = (double*)ws;
    unsigned* count = (unsigned*)(ws + 8);
    float* csq = (float*)(ws + WS_CSQ_OFF);
    float* zsq32 = (float*)(ws + WS_ZSQ_OFF);
    int* worklist = (int*)(ws + WS_WORK_OFF);
    unsigned long long* pack = (unsigned long long*)(ws + WS_PACK_OFF);
    float* cbT = (float*)(ws + WS_CBT_OFF);

    hipMemsetAsync(d_ws, 0, 16, stream);                        // acc=0, count=0
    hipMemsetAsync(ws + WS_PACK_OFF, 0xFF, ZN * 8, stream);     // pack = UINT64_MAX

    vq_csq<<<KK / 256, 256, 0, stream>>>(cb, csq);
    vq_transpose<<<KK * DD / 256, 256, 0, stream>>>(cb, cbT);
    vq_argmin<<<ZN / 256, 256, 0, stream>>>(z, cb, csq, zsq32, idxf_out, count, worklist);
    vq_refine<<<2048, 256, 0, stream>>>(z, cbT, csq, zsq32, count, worklist, pack);
    vq_writeback<<<ZN / 256, 256, 0, stream>>>(count, worklist, pack, idxf_out);
    vq_gather_loss<<<ZN / 256, 256, 0, stream>>>(z, cb, idxf_out, zq_out, acc);
    vq_finalize<<<1, 1, 0, stream>>>(acc, loss_out);
}

// Round 6
// 715.267 us; speedup vs baseline: 1.7385x; 1.0052x over previous
//
#include <hip/hip_runtime.h>

#define ZN 131072          // B*H*W rows
#define DD 64              // embedding dim
#define KK 1024            // codebook entries
#define BSTRIDE 262144     // 64*64*64 (per-batch stride in z)
#define DSTRIDE 4096       // per-d stride in z (H*W)
#define ZQ_ELEMS 8388608   // 32*64*64*64

// ---- workspace layout ----
// [0,8)                double   loss accumulator
// [8,12)               unsigned flagged-row count
// [16,4112)            float    csq32[1024]    (numpy-emulated fp32)
// [4112,528400)        float    zsq32[131072]  (numpy-emulated fp32)
// [528400,1052688)     int      worklist[131072]
// [1052688,2101264)    u64      pack[131072]   (ordered_dist<<32 | k)
// [2101264,2363408)    float    cbT[64][1024]  (transposed codebook)
#define WS_CSQ_OFF   16
#define WS_ZSQ_OFF   4112
#define WS_WORK_OFF  528400
#define WS_PACK_OFF  1052688
#define WS_CBT_OFF   2101264

typedef float v2f __attribute__((ext_vector_type(2)));

// numpy-emulated fp32 sum of a[i]^2 over 64 elems (pairwise, 8 accumulators).
__device__ __forceinline__ float np_sumsq64(const float* a) {
    float r0 = __fmul_rn(a[0], a[0]), r1 = __fmul_rn(a[1], a[1]);
    float r2 = __fmul_rn(a[2], a[2]), r3 = __fmul_rn(a[3], a[3]);
    float r4 = __fmul_rn(a[4], a[4]), r5 = __fmul_rn(a[5], a[5]);
    float r6 = __fmul_rn(a[6], a[6]), r7 = __fmul_rn(a[7], a[7]);
#pragma unroll
    for (int i = 8; i < 64; i += 8) {
        r0 = __fadd_rn(r0, __fmul_rn(a[i + 0], a[i + 0]));
        r1 = __fadd_rn(r1, __fmul_rn(a[i + 1], a[i + 1]));
        r2 = __fadd_rn(r2, __fmul_rn(a[i + 2], a[i + 2]));
        r3 = __fadd_rn(r3, __fmul_rn(a[i + 3], a[i + 3]));
        r4 = __fadd_rn(r4, __fmul_rn(a[i + 4], a[i + 4]));
        r5 = __fadd_rn(r5, __fmul_rn(a[i + 5], a[i + 5]));
        r6 = __fadd_rn(r6, __fmul_rn(a[i + 6], a[i + 6]));
        r7 = __fadd_rn(r7, __fmul_rn(a[i + 7], a[i + 7]));
    }
    return __fadd_rn(__fadd_rn(__fadd_rn(r0, r1), __fadd_rn(r2, r3)),
                     __fadd_rn(__fadd_rn(r4, r5), __fadd_rn(r6, r7)));
}

__global__ __launch_bounds__(256) void vq_csq(const float* __restrict__ cb,
                                              float* __restrict__ csq) {
    int k = blockIdx.x * 256 + threadIdx.x;
    csq[k] = np_sumsq64(cb + k * DD);
}

// cbT[d][k] = cb[k][d]
__global__ __launch_bounds__(256) void vq_transpose(const float* __restrict__ cb,
                                                    float* __restrict__ cbT) {
    int i = blockIdx.x * 256 + threadIdx.x;  // i = d*1024 + k
    int d = i >> 10, k = i & 1023;
    cbT[i] = cb[k * DD + d];
}

// -------- fp32 prefilter argmin: 1 row/thread, packed-fp32 inner loop ------
// k is a uniform loop var -> codebook & csq come in via s_load (SGPR
// broadcast). z row in 32 x float2 VGPRs. waves_per_eu(2) = min 2 (VGPR cap
// 256, no spill) with NO max cap: at 88 VGPRs the HW hosts 5 waves/SIMD.
__global__ __attribute__((amdgpu_waves_per_eu(2))) __launch_bounds__(256)
void vq_argmin(const float* __restrict__ z,
               const float* __restrict__ cb,
               const float* __restrict__ csq,
               float* __restrict__ zsq32,
               float* __restrict__ idxf_out,
               unsigned* __restrict__ count,
               int* __restrict__ worklist) {
    int n = blockIdx.x * 256 + threadIdx.x;
    int b = n >> 12, p = n & 4095;
    const float* zp = z + (size_t)b * BSTRIDE + p;

    v2f zr[32];
#pragma unroll
    for (int j = 0; j < 32; ++j) {  // coalesced across lanes (stride-4096 per d)
        zr[j].x = zp[(size_t)(2 * j + 0) * DSTRIDE];
        zr[j].y = zp[(size_t)(2 * j + 1) * DSTRIDE];
    }

    // numpy-emulated fp32 ||z||^2 (same pairwise-8 order as np.sum)
    {
#define ZA(i) (((i) & 1) ? zr[(i) >> 1].y : zr[(i) >> 1].x)
        float r[8];
#pragma unroll
        for (int j = 0; j < 8; ++j) r[j] = __fmul_rn(ZA(j), ZA(j));
#pragma unroll
        for (int i = 8; i < 64; i += 8)
#pragma unroll
            for (int j = 0; j < 8; ++j)
                r[j] = __fadd_rn(r[j], __fmul_rn(ZA(i + j), ZA(i + j)));
        zsq32[n] = __fadd_rn(__fadd_rn(__fadd_rn(r[0], r[1]), __fadd_rn(r[2], r[3])),
                             __fadd_rn(__fadd_rn(r[4], r[5]), __fadd_rn(r[6], r[7])));
#undef ZA
    }

    float min1 = 3.4e38f, min2 = 3.4e38f;
    int best = 0;
#pragma unroll 2
    for (int k = 0; k < KK; ++k) {  // k uniform -> scalar loads
        const v2f* c = (const v2f*)(cb + k * DD);
        v2f a0 = {0.f, 0.f}, a1 = {0.f, 0.f}, a2 = {0.f, 0.f}, a3 = {0.f, 0.f};
#pragma unroll
        for (int j = 0; j < 32; j += 4) {
            a0 = __builtin_elementwise_fma(zr[j + 0], c[j + 0], a0);
            a1 = __builtin_elementwise_fma(zr[j + 1], c[j + 1], a1);
            a2 = __builtin_elementwise_fma(zr[j + 2], c[j + 2], a2);
            a3 = __builtin_elementwise_fma(zr[j + 3], c[j + 3], a3);
        }
        v2f s = (a0 + a1) + (a2 + a3);
        float dot = s.x + s.y;
        float dist = fmaf(-2.f, dot, csq[k]);
        bool lt = dist < min1;  // strict: keeps lowest k on ties
        float old1 = min1;
        min1 = lt ? dist : min1;
        min2 = lt ? old1 : fminf(min2, dist);
        best = lt ? k : best;
    }

    idxf_out[n] = (float)best;
    // reference fp32 rounding noise can only flip ranking for gaps < ~1.5e-5;
    // flag with wide margin -> exact reference-arithmetic emulation pass.
    if (min2 - min1 < 2e-4f) worklist[atomicAdd(count, 1u)] = n;
}

// -------- reference-fp32-emulated argmin for flagged rows --------
// work item = (flagged row r, code k); lanes <-> consecutive k (coalesced cbT);
// each wave = 64 k's of one row -> shuffle-min -> one atomicMin per wave.
__global__ __launch_bounds__(256) void vq_refine(const float* __restrict__ z,
                                                 const float* __restrict__ cbT,
                                                 const float* __restrict__ csq,
                                                 const float* __restrict__ zsq32,
                                                 const unsigned* __restrict__ count,
                                                 const int* __restrict__ worklist,
                                                 unsigned long long* __restrict__ pack) {
    unsigned cnt = *count;
    unsigned long long total = (unsigned long long)cnt << 10;
    unsigned long long stride = (unsigned long long)gridDim.x * 256;
    for (unsigned long long w = blockIdx.x * 256 + threadIdx.x; w < total; w += stride) {
        unsigned r = (unsigned)(w >> 10);
        unsigned k = (unsigned)(w & 1023);
        int n = worklist[r];
        int b = n >> 12, p = n & 4095;
        const float* zp = z + (size_t)b * BSTRIDE + p;

        double a0 = 0.0, a1 = 0.0, a2 = 0.0, a3 = 0.0;
#pragma unroll
        for (int d = 0; d < DD; d += 4) {
            a0 = fma((double)zp[(size_t)(d + 0) * DSTRIDE], (double)cbT[(d + 0) * KK + k], a0);
            a1 = fma((double)zp[(size_t)(d + 1) * DSTRIDE], (double)cbT[(d + 1) * KK + k], a1);
            a2 = fma((double)zp[(size_t)(d + 2) * DSTRIDE], (double)cbT[(d + 2) * KK + k], a2);
            a3 = fma((double)zp[(size_t)(d + 3) * DSTRIDE], (double)cbT[(d + 3) * KK + k], a3);
        }
        double dot = (a0 + a1) + (a2 + a3);
        float twoC = (float)(2.0 * dot);               // ~sgemm output, correctly rounded
        float dist = __fsub_rn(__fadd_rn(zsq32[n], csq[k]), twoC);  // reference fp32 ops

        unsigned ub = __float_as_uint(dist);
        ub = (ub & 0x80000000u) ? ~ub : (ub | 0x80000000u);  // order-preserving map
        unsigned long long pk = ((unsigned long long)ub << 32) | k;  // ties -> lowest k
#pragma unroll
        for (int off = 32; off; off >>= 1) {
            unsigned long long o = (unsigned long long)__shfl_xor((long long)pk, off, 64);
            pk = pk < o ? pk : o;
        }
        if ((threadIdx.x & 63) == 0) atomicMin(&pack[r], pk);
    }
}

__global__ __launch_bounds__(256) void vq_writeback(const unsigned* __restrict__ count,
                                                    const int* __restrict__ worklist,
                                                    const unsigned long long* __restrict__ pack,
                                                    float* __restrict__ idxf_out) {
    unsigned i = blockIdx.x * 256 + threadIdx.x;
    if (i < *count)
        idxf_out[worklist[i]] = (float)(unsigned)(pack[i] & 0xFFFFFFFFull);
}

// -------- gather z_q + fused loss partial reduction --------
__global__ __launch_bounds__(256) void vq_gather_loss(const float* __restrict__ z,
                                                      const float* __restrict__ cb,
                                                      const float* __restrict__ idxf,
                                                      float* __restrict__ zq_out,
                                                      double* __restrict__ acc) {
    int n = blockIdx.x * 256 + threadIdx.x;
    int b = n >> 12, p = n & 4095;
    const float* zp = z + (size_t)b * BSTRIDE + p;
    float* qp = zq_out + (size_t)b * BSTRIDE + p;
    int k = (int)idxf[n];
    const float* c = cb + k * DD;

    float s = 0.f;
#pragma unroll
    for (int d = 0; d < DD; ++d) {
        float q = c[d];
        float diff = q - zp[(size_t)d * DSTRIDE];
        s = fmaf(diff, diff, s);
        qp[(size_t)d * DSTRIDE] = q;  // z_q_st == z_q numerically
    }

#pragma unroll
    for (int off = 32; off; off >>= 1) s += __shfl_down(s, off, 64);
    __shared__ float partial[4];
    if ((threadIdx.x & 63) == 0) partial[threadIdx.x >> 6] = s;
    __syncthreads();
    if (threadIdx.x == 0) {
        float t = (partial[0] + partial[1]) + (partial[2] + partial[3]);
        atomicAdd(acc, (double)t);
    }
}

__global__ void vq_finalize(const double* __restrict__ acc, float* __restrict__ loss_out) {
    *loss_out = (float)(1.25 * (*acc) / (double)ZQ_ELEMS);
}

extern "C" void kernel_launch(void* const* d_in, const int* in_sizes, int n_in,
                              void* d_out, int out_size, void* d_ws, size_t ws_size,
                              hipStream_t stream) {
    const float* z = (const float*)d_in[0];
    const float* cb = (const float*)d_in[1];
    float* out = (float*)d_out;

    float* zq_out = out;                   // [0, 8388608)
    float* loss_out = out + ZQ_ELEMS;      // [8388608]
    float* idxf_out = out + ZQ_ELEMS + 1;  // [8388609, +131072)

    char* ws = (char*)d_ws;
    double* acc = (double*)ws;
    unsigned* count = (unsigned*)(ws + 8);
    float* csq = (float*)(ws + WS_CSQ_OFF);
    float* zsq32 = (float*)(ws + WS_ZSQ_OFF);
    int* worklist = (int*)(ws + WS_WORK_OFF);
    unsigned long long* pack = (unsigned long long*)(ws + WS_PACK_OFF);
    float* cbT = (float*)(ws + WS_CBT_OFF);

    hipMemsetAsync(d_ws, 0, 16, stream);                        // acc=0, count=0
    hipMemsetAsync(ws + WS_PACK_OFF, 0xFF, ZN * 8, stream);     // pack = UINT64_MAX

    vq_csq<<<KK / 256, 256, 0, stream>>>(cb, csq);
    vq_transpose<<<KK * DD / 256, 256, 0, stream>>>(cb, cbT);
    vq_argmin<<<ZN / 256, 256, 0, stream>>>(z, cb, csq, zsq32, idxf_out, count, worklist);
    vq_refine<<<2048, 256, 0, stream>>>(z, cbT, csq, zsq32, count, worklist, pack);
    vq_writeback<<<ZN / 256, 256, 0, stream>>>(count, worklist, pack, idxf_out);
    vq_gather_loss<<<ZN / 256, 256, 0, stream>>>(z, cb, idxf_out, zq_out, acc);
    vq_finalize<<<1, 1, 0, stream>>>(acc, loss_out);
}

// Round 7
// 513.407 us; speedup vs baseline: 2.4220x; 1.3932x over previous
//
#include <hip/hip_runtime.h>

#define ZN 131072          // B*H*W rows
#define DD 64              // embedding dim
#define KK 1024            // codebook entries
#define BSTRIDE 262144     // 64*64*64 (per-batch stride in z)
#define DSTRIDE 4096       // per-d stride in z (H*W)
#define ZQ_ELEMS 8388608   // 32*64*64*64

// ---- workspace layout ----
// [0,8)                double   loss accumulator
// [8,12)               unsigned flagged-row count
// [16,4112)            float    csq32[1024]    (numpy-emulated fp32)
// [4112,528400)        float    zsq32[131072]  (numpy-emulated fp32)
// [528400,1052688)     int      worklist[131072]
// [1052688,2101264)    u64      pack[131072]   (ordered_dist<<32 | k)
// [2101264,2363408)    float    cbT[64][1024]  (transposed codebook)
#define WS_CSQ_OFF   16
#define WS_ZSQ_OFF   4112
#define WS_WORK_OFF  528400
#define WS_PACK_OFF  1052688
#define WS_CBT_OFF   2101264

typedef float v2f __attribute__((ext_vector_type(2)));

// numpy-emulated fp32 sum of a[i]^2 over 64 elems (pairwise, 8 accumulators).
__device__ __forceinline__ float np_sumsq64(const float* a) {
    float r0 = __fmul_rn(a[0], a[0]), r1 = __fmul_rn(a[1], a[1]);
    float r2 = __fmul_rn(a[2], a[2]), r3 = __fmul_rn(a[3], a[3]);
    float r4 = __fmul_rn(a[4], a[4]), r5 = __fmul_rn(a[5], a[5]);
    float r6 = __fmul_rn(a[6], a[6]), r7 = __fmul_rn(a[7], a[7]);
#pragma unroll
    for (int i = 8; i < 64; i += 8) {
        r0 = __fadd_rn(r0, __fmul_rn(a[i + 0], a[i + 0]));
        r1 = __fadd_rn(r1, __fmul_rn(a[i + 1], a[i + 1]));
        r2 = __fadd_rn(r2, __fmul_rn(a[i + 2], a[i + 2]));
        r3 = __fadd_rn(r3, __fmul_rn(a[i + 3], a[i + 3]));
        r4 = __fadd_rn(r4, __fmul_rn(a[i + 4], a[i + 4]));
        r5 = __fadd_rn(r5, __fmul_rn(a[i + 5], a[i + 5]));
        r6 = __fadd_rn(r6, __fmul_rn(a[i + 6], a[i + 6]));
        r7 = __fadd_rn(r7, __fmul_rn(a[i + 7], a[i + 7]));
    }
    return __fadd_rn(__fadd_rn(__fadd_rn(r0, r1), __fadd_rn(r2, r3)),
                     __fadd_rn(__fadd_rn(r4, r5), __fadd_rn(r6, r7)));
}

__global__ __launch_bounds__(256) void vq_csq(const float* __restrict__ cb,
                                              float* __restrict__ csq) {
    int k = blockIdx.x * 256 + threadIdx.x;
    csq[k] = np_sumsq64(cb + k * DD);
}

// cbT[d][k] = cb[k][d]
__global__ __launch_bounds__(256) void vq_transpose(const float* __restrict__ cb,
                                                    float* __restrict__ cbT) {
    int i = blockIdx.x * 256 + threadIdx.x;  // i = d*1024 + k
    int d = i >> 10, k = i & 1023;
    cbT[i] = cb[k * DD + d];
}

// -------- fp32 prefilter argmin --------
// block = 256 threads = 64 rows x 4 waves; wave w scans codes
// [w*256, w*256+256) — k-base pinned to an SGPR via readfirstlane so
// codebook/csq loads stay scalar (s_load broadcast). z row in 32 x float2
// VGPRs; waves_per_eu(2) grants 256 VGPRs (no spill). Grid = 2048 blocks
// -> ~5 waves/SIMD to hide the s_load chain. LDS merge of the 4 k-chunks:
// global min2 = min(winner.min2, losers' min1).
__global__ __attribute__((amdgpu_waves_per_eu(2))) __launch_bounds__(256)
void vq_argmin(const float* __restrict__ z,
               const float* __restrict__ cb,
               const float* __restrict__ csq,
               float* __restrict__ zsq32,
               float* __restrict__ idxf_out,
               unsigned* __restrict__ count,
               int* __restrict__ worklist) {
    int tl = threadIdx.x & 63;
    int wv = __builtin_amdgcn_readfirstlane(threadIdx.x >> 6);  // SGPR wave id
    int n = blockIdx.x * 64 + tl;
    int b = n >> 12, p = n & 4095;
    const float* zp = z + (size_t)b * BSTRIDE + p;

    v2f zr[32];
#pragma unroll
    for (int j = 0; j < 32; ++j) {  // coalesced across lanes (stride-4096 per d)
        zr[j].x = zp[(size_t)(2 * j + 0) * DSTRIDE];
        zr[j].y = zp[(size_t)(2 * j + 1) * DSTRIDE];
    }

    if (wv == 0) {
        // numpy-emulated fp32 ||z||^2 (same pairwise-8 order as np.sum)
#define ZA(i) (((i) & 1) ? zr[(i) >> 1].y : zr[(i) >> 1].x)
        float r[8];
#pragma unroll
        for (int j = 0; j < 8; ++j) r[j] = __fmul_rn(ZA(j), ZA(j));
#pragma unroll
        for (int i = 8; i < 64; i += 8)
#pragma unroll
            for (int j = 0; j < 8; ++j)
                r[j] = __fadd_rn(r[j], __fmul_rn(ZA(i + j), ZA(i + j)));
        zsq32[n] = __fadd_rn(__fadd_rn(__fadd_rn(r[0], r[1]), __fadd_rn(r[2], r[3])),
                             __fadd_rn(__fadd_rn(r[4], r[5]), __fadd_rn(r[6], r[7])));
#undef ZA
    }

    float min1 = 3.4e38f, min2 = 3.4e38f;
    int best = 0;
    int kbase = wv << 8;  // SGPR
#pragma unroll 2
    for (int kk = 0; kk < 256; ++kk) {
        int k = kbase + kk;  // uniform -> scalar loads
        const v2f* c = (const v2f*)(cb + k * DD);
        v2f a0 = {0.f, 0.f}, a1 = {0.f, 0.f}, a2 = {0.f, 0.f}, a3 = {0.f, 0.f};
#pragma unroll
        for (int j = 0; j < 32; j += 4) {
            a0 = __builtin_elementwise_fma(zr[j + 0], c[j + 0], a0);
            a1 = __builtin_elementwise_fma(zr[j + 1], c[j + 1], a1);
            a2 = __builtin_elementwise_fma(zr[j + 2], c[j + 2], a2);
            a3 = __builtin_elementwise_fma(zr[j + 3], c[j + 3], a3);
        }
        v2f s = (a0 + a1) + (a2 + a3);
        float dot = s.x + s.y;
        float dist = fmaf(-2.f, dot, csq[k]);
        bool lt = dist < min1;  // strict: keeps lowest k on ties
        float old1 = min1;
        min1 = lt ? dist : min1;
        min2 = lt ? old1 : fminf(min2, dist);
        best = lt ? k : best;
    }

    __shared__ float smin1[4][64];
    __shared__ float smin2[4][64];
    __shared__ int sbest[4][64];
    smin1[wv][tl] = min1;
    smin2[wv][tl] = min2;
    sbest[wv][tl] = best;
    __syncthreads();

    if (wv == 0) {
        float g1 = smin1[0][tl], g2 = smin2[0][tl];
        int gb = sbest[0][tl];
#pragma unroll
        for (int c = 1; c < 4; ++c) {
            float c1 = smin1[c][tl];
            if (c1 < g1) {                 // strict: ties keep lower-k chunk
                g2 = fminf(g1, smin2[c][tl]);
                gb = sbest[c][tl];
                g1 = c1;
            } else {
                g2 = fminf(g2, c1);
            }
        }
        idxf_out[n] = (float)gb;
        // reference fp32 rounding noise can only flip ranking for gaps
        // < ~1.6e-5; flag with 12x margin -> exact emulation pass.
        if (g2 - g1 < 2e-4f) worklist[atomicAdd(count, 1u)] = n;
    }
}

// -------- reference-fp32-emulated argmin for flagged rows --------
// work item = (flagged row r, code k); lanes <-> consecutive k (coalesced cbT);
// each wave = 64 k's of one row -> shuffle-min -> one atomicMin per wave.
__global__ __launch_bounds__(256) void vq_refine(const float* __restrict__ z,
                                                 const float* __restrict__ cbT,
                                                 const float* __restrict__ csq,
                                                 const float* __restrict__ zsq32,
                                                 const unsigned* __restrict__ count,
                                                 const int* __restrict__ worklist,
                                                 unsigned long long* __restrict__ pack) {
    unsigned cnt = *count;
    unsigned long long total = (unsigned long long)cnt << 10;
    unsigned long long stride = (unsigned long long)gridDim.x * 256;
    for (unsigned long long w = blockIdx.x * 256 + threadIdx.x; w < total; w += stride) {
        unsigned r = (unsigned)(w >> 10);
        unsigned k = (unsigned)(w & 1023);
        int n = worklist[r];
        int b = n >> 12, p = n & 4095;
        const float* zp = z + (size_t)b * BSTRIDE + p;

        double a0 = 0.0, a1 = 0.0, a2 = 0.0, a3 = 0.0;
#pragma unroll
        for (int d = 0; d < DD; d += 4) {
            a0 = fma((double)zp[(size_t)(d + 0) * DSTRIDE], (double)cbT[(d + 0) * KK + k], a0);
            a1 = fma((double)zp[(size_t)(d + 1) * DSTRIDE], (double)cbT[(d + 1) * KK + k], a1);
            a2 = fma((double)zp[(size_t)(d + 2) * DSTRIDE], (double)cbT[(d + 2) * KK + k], a2);
            a3 = fma((double)zp[(size_t)(d + 3) * DSTRIDE], (double)cbT[(d + 3) * KK + k], a3);
        }
        double dot = (a0 + a1) + (a2 + a3);
        float twoC = (float)(2.0 * dot);               // ~sgemm output, correctly rounded
        float dist = __fsub_rn(__fadd_rn(zsq32[n], csq[k]), twoC);  // reference fp32 ops

        unsigned ub = __float_as_uint(dist);
        ub = (ub & 0x80000000u) ? ~ub : (ub | 0x80000000u);  // order-preserving map
        unsigned long long pk = ((unsigned long long)ub << 32) | k;  // ties -> lowest k
#pragma unroll
        for (int off = 32; off; off >>= 1) {
            unsigned long long o = (unsigned long long)__shfl_xor((long long)pk, off, 64);
            pk = pk < o ? pk : o;
        }
        if ((threadIdx.x & 63) == 0) atomicMin(&pack[r], pk);
    }
}

__global__ __launch_bounds__(256) void vq_writeback(const unsigned* __restrict__ count,
                                                    const int* __restrict__ worklist,
                                                    const unsigned long long* __restrict__ pack,
                                                    float* __restrict__ idxf_out) {
    unsigned i = blockIdx.x * 256 + threadIdx.x;
    if (i < *count)
        idxf_out[worklist[i]] = (float)(unsigned)(pack[i] & 0xFFFFFFFFull);
}

// -------- gather z_q + fused loss partial reduction --------
__global__ __launch_bounds__(256) void vq_gather_loss(const float* __restrict__ z,
                                                      const float* __restrict__ cb,
                                                      const float* __restrict__ idxf,
                                                      float* __restrict__ zq_out,
                                                      double* __restrict__ acc) {
    int n = blockIdx.x * 256 + threadIdx.x;
    int b = n >> 12, p = n & 4095;
    const float* zp = z + (size_t)b * BSTRIDE + p;
    float* qp = zq_out + (size_t)b * BSTRIDE + p;
    int k = (int)idxf[n];
    const float* c = cb + k * DD;

    float s = 0.f;
#pragma unroll
    for (int d = 0; d < DD; ++d) {
        float q = c[d];
        float diff = q - zp[(size_t)d * DSTRIDE];
        s = fmaf(diff, diff, s);
        qp[(size_t)d * DSTRIDE] = q;  // z_q_st == z_q numerically
    }

#pragma unroll
    for (int off = 32; off; off >>= 1) s += __shfl_down(s, off, 64);
    __shared__ float partial[4];
    if ((threadIdx.x & 63) == 0) partial[threadIdx.x >> 6] = s;
    __syncthreads();
    if (threadIdx.x == 0) {
        float t = (partial[0] + partial[1]) + (partial[2] + partial[3]);
        atomicAdd(acc, (double)t);
    }
}

__global__ void vq_finalize(const double* __restrict__ acc, float* __restrict__ loss_out) {
    *loss_out = (float)(1.25 * (*acc) / (double)ZQ_ELEMS);
}

extern "C" void kernel_launch(void* const* d_in, const int* in_sizes, int n_in,
                              void* d_out, int out_size, void* d_ws, size_t ws_size,
                              hipStream_t stream) {
    const float* z = (const float*)d_in[0];
    const float* cb = (const float*)d_in[1];
    float* out = (float*)d_out;

    float* zq_out = out;                   // [0, 8388608)
    float* loss_out = out + ZQ_ELEMS;      // [8388608]
    float* idxf_out = out + ZQ_ELEMS + 1;  // [8388609, +131072)

    char* ws = (char*)d_ws;
    double* acc = (double*)ws;
    unsigned* count = (unsigned*)(ws + 8);
    float* csq = (float*)(ws + WS_CSQ_OFF);
    float* zsq32 = (float*)(ws + WS_ZSQ_OFF);
    int* worklist = (int*)(ws + WS_WORK_OFF);
    unsigned long long* pack = (unsigned long long*)(ws + WS_PACK_OFF);
    float* cbT = (float*)(ws + WS_CBT_OFF);

    hipMemsetAsync(d_ws, 0, 16, stream);                        // acc=0, count=0
    hipMemsetAsync(ws + WS_PACK_OFF, 0xFF, ZN * 8, stream);     // pack = UINT64_MAX

    vq_csq<<<KK / 256, 256, 0, stream>>>(cb, csq);
    vq_transpose<<<KK * DD / 256, 256, 0, stream>>>(cb, cbT);
    vq_argmin<<<ZN / 64, 256, 0, stream>>>(z, cb, csq, zsq32, idxf_out, count, worklist);
    vq_refine<<<2048, 256, 0, stream>>>(z, cbT, csq, zsq32, count, worklist, pack);
    vq_writeback<<<ZN / 256, 256, 0, stream>>>(count, worklist, pack, idxf_out);
    vq_gather_loss<<<ZN / 256, 256, 0, stream>>>(z, cb, idxf_out, zq_out, acc);
    vq_finalize<<<1, 1, 0, stream>>>(acc, loss_out);
}